// Round 7
// baseline (6350.735 us; speedup 1.0000x reference)
//
#include <hip/hip_runtime.h>
#include <stdint.h>
#include <stddef.h>

// Problem dims
#define Bn   64
#define Tn   512
#define DINn 512
#define Hn   1024
#define OUTn 128

typedef __attribute__((ext_vector_type(4))) float f32x4;
typedef __attribute__((ext_vector_type(8))) short short8;
typedef __attribute__((ext_vector_type(4))) unsigned int u32x4;

__device__ __forceinline__ unsigned short f2bf(float f){
  unsigned int x = __builtin_bit_cast(unsigned int, f);
  x += 0x7fffu + ((x >> 16) & 1u);           // RNE (values bounded, no NaN/inf)
  return (unsigned short)(x >> 16);
}
__device__ __forceinline__ float bf2f(unsigned short u){
  return __builtin_bit_cast(float, (unsigned int)u << 16);
}
__device__ __forceinline__ float tanh_fast(float v){
  float e = __expf(2.0f * v);
  return 1.0f - 2.0f / (e + 1.0f);
}

// ---- protocol primitives ----
// FAST: XCD-local L2 protocol — sc0 stores (write-through to XCD L2) + buffer_inv sc0
//       (local L1 invalidate) before sc0 loads. Engaged only after the on-device
//       self-test proves this exact sequence on every XCD (r6 lesson: sc0 loads
//       without inv hit stale L1 lines).
// !FAST: sc0 sc1 (MALL) protocol — r4/r5-proven, placement-independent.
template<bool FAST>
__device__ __forceinline__ void st_flag(unsigned int* p, unsigned v){
  if constexpr (FAST)
    asm volatile("global_store_dword %0, %1, off sc0" :: "v"(p), "v"(v) : "memory");
  else
    asm volatile("global_store_dword %0, %1, off sc0 sc1" :: "v"(p), "v"(v) : "memory");
}
template<bool FAST>
__device__ __forceinline__ void st16(unsigned short* p, u32x4 v){
  if constexpr (FAST)
    asm volatile("global_store_dwordx4 %0, %1, off sc0" :: "v"(p), "v"(v) : "memory");
  else
    asm volatile("global_store_dwordx4 %0, %1, off sc0 sc1" :: "v"(p), "v"(v) : "memory");
}
__device__ __forceinline__ unsigned umin4(u32x4 a){
  unsigned m0 = a[0] < a[1] ? a[0] : a[1];
  unsigned m1 = a[2] < a[3] ? a[2] : a[3];
  return m0 < m1 ? m0 : m1;
}
__device__ __forceinline__ unsigned ld_line8_slow(const unsigned int* p){
  u32x4 a, b;
  asm volatile("global_load_dwordx4 %0, %2, off sc0 sc1\n\t"
               "global_load_dwordx4 %1, %3, off sc0 sc1\n\t"
               "s_waitcnt vmcnt(0)"
               : "=&v"(a), "=&v"(b) : "v"(p), "v"(p + 4) : "memory");
  unsigned ma = umin4(a), mb = umin4(b);
  return ma < mb ? ma : mb;
}
__device__ __forceinline__ unsigned ld_line8_fast(const unsigned int* p){
  u32x4 a, b;
  asm volatile("buffer_inv sc0\n\t"
               "s_waitcnt vmcnt(0)\n\t"
               "global_load_dwordx4 %0, %2, off sc0\n\t"
               "global_load_dwordx4 %1, %3, off sc0\n\t"
               "s_waitcnt vmcnt(0)"
               : "=&v"(a), "=&v"(b) : "v"(p), "v"(p + 4) : "memory");
  unsigned ma = umin4(a), mb = umin4(b);
  return ma < mb ? ma : mb;
}
__device__ __forceinline__ unsigned ld1_fast(const unsigned int* p){
  unsigned v;
  asm volatile("buffer_inv sc0\n\t"
               "s_waitcnt vmcnt(0)\n\t"
               "global_load_dword %0, %1, off sc0\n\t"
               "s_waitcnt vmcnt(0)" : "=&v"(v) : "v"(p) : "memory");
  return v;
}
// Bounded waits (tid0 only). Worst case returns late -> visibly wrong, never a hang.
template<bool FAST>
__device__ __forceinline__ void wait8(const unsigned int* p, unsigned want){
  if (!want) return;
  for (int i = 0; i < (1 << 16); ++i){
    unsigned m = FAST ? ld_line8_fast(p) : ld_line8_slow(p);
    if (m >= want) return;
    if (i > 16) __builtin_amdgcn_s_sleep(1);
  }
}
template<bool FAST>
__device__ __forceinline__ void wait8_dual(const unsigned int* p1, unsigned w1,
                                           const unsigned int* p2, unsigned w2){
  if (!w2){ wait8<FAST>(p1, w1); return; }
  for (int i = 0; i < (1 << 16); ++i){
    unsigned m1 = FAST ? ld_line8_fast(p1) : ld_line8_slow(p1);
    unsigned m2 = FAST ? ld_line8_fast(p2) : ld_line8_slow(p2);
    if (m1 >= w1 && m2 >= w2) return;
    if (i > 16) __builtin_amdgcn_s_sleep(1);
  }
}

// Linear 16KB tile copy global->LDS (tiles are pre-permuted in chunk order).
// L1 freshness in FAST mode: tid0's poll did buffer_inv after the flag was set and
// nothing re-caches these lines before the barrier.
template<bool FAST>
__device__ __forceinline__ void stage_lin(const unsigned short* base, unsigned short* hl, int tid){
  const unsigned short* p0 = base + (size_t)tid * 8;
  const unsigned short* p1 = p0 + 512 * 8;
  u32x4 v0, v1;
  if constexpr (FAST)
    asm volatile("global_load_dwordx4 %0, %2, off sc0\n\t"
                 "global_load_dwordx4 %1, %3, off sc0\n\t"
                 "s_waitcnt vmcnt(0)"
                 : "=&v"(v0), "=&v"(v1) : "v"(p0), "v"(p1) : "memory");
  else
    asm volatile("global_load_dwordx4 %0, %2, off sc0 sc1\n\t"
                 "global_load_dwordx4 %1, %3, off sc0 sc1\n\t"
                 "s_waitcnt vmcnt(0)"
                 : "=&v"(v0), "=&v"(v1) : "v"(p0), "v"(p1) : "memory");
  *(u32x4*)((char*)hl + tid * 16) = v0;
  *(u32x4*)((char*)hl + tid * 16 + 8192) = v1;
}
// 4 bf16 loads at short-stride 8 (chunk-order row walk), 64B window.
template<bool FAST>
__device__ __forceinline__ void ld4_chunk(const unsigned short* p, float* pv){
  unsigned u0,u1,u2,u3;
  if constexpr (FAST)
    asm volatile("global_load_ushort %0, %4, off sc0\n\t"
                 "global_load_ushort %1, %5, off sc0\n\t"
                 "global_load_ushort %2, %6, off sc0\n\t"
                 "global_load_ushort %3, %7, off sc0\n\t"
                 "s_waitcnt vmcnt(0)"
                 : "=&v"(u0), "=&v"(u1), "=&v"(u2), "=&v"(u3)
                 : "v"(p), "v"(p + 8), "v"(p + 16), "v"(p + 24) : "memory");
  else
    asm volatile("global_load_ushort %0, %4, off sc0 sc1\n\t"
                 "global_load_ushort %1, %5, off sc0 sc1\n\t"
                 "global_load_ushort %2, %6, off sc0 sc1\n\t"
                 "global_load_ushort %3, %7, off sc0 sc1\n\t"
                 "s_waitcnt vmcnt(0)"
                 : "=&v"(u0), "=&v"(u1), "=&v"(u2), "=&v"(u3)
                 : "v"(p), "v"(p + 8), "v"(p + 16), "v"(p + 24) : "memory");
  pv[0] = bf2f((unsigned short)u0); pv[1] = bf2f((unsigned short)u1);
  pv[2] = bf2f((unsigned short)u2); pv[3] = bf2f((unsigned short)u3);
}

// MFMA sweep over K=1024: chunk c=(n>>3)*8+r holds h[r][(n>>3)*8..+8]. Read addr
// kk*512 + kh*128 + lrow*16: per kk a wave reads 512 consecutive bytes (conflict-free).
__device__ __forceinline__ f32x4 mfma_tile(const char* lbase, const short8* wf, int lrow, int kh){
  f32x4 a0 = {0.f,0.f,0.f,0.f}, a1 = a0, a2 = a0, a3 = a0;
  int rb = kh * 128 + lrow * 16;
#pragma unroll
  for (int kk = 0; kk < 8; ++kk)
    a0 = __builtin_amdgcn_mfma_f32_16x16x32_bf16(*(const short8*)(lbase + kk*512 + rb), wf[kk], a0, 0,0,0);
#pragma unroll
  for (int kk = 8; kk < 16; ++kk)
    a1 = __builtin_amdgcn_mfma_f32_16x16x32_bf16(*(const short8*)(lbase + kk*512 + rb), wf[kk], a1, 0,0,0);
#pragma unroll
  for (int kk = 16; kk < 24; ++kk)
    a2 = __builtin_amdgcn_mfma_f32_16x16x32_bf16(*(const short8*)(lbase + kk*512 + rb), wf[kk], a2, 0,0,0);
#pragma unroll
  for (int kk = 24; kk < 32; ++kk)
    a3 = __builtin_amdgcn_mfma_f32_16x16x32_bf16(*(const short8*)(lbase + kk*512 + rb), wf[kk], a3, 0,0,0);
  return (a0 + a1) + (a2 + a3);
}

// ---------------- elementwise f32 -> bf16 (vectorized x8) ----------------
__global__ void cvt_bf16x8(const float* __restrict__ in, unsigned short* __restrict__ out,
                           long long n8){
  long long i = (long long)blockIdx.x * blockDim.x + threadIdx.x;
  long long stride = (long long)gridDim.x * blockDim.x;
  for (; i < n8; i += stride){
    const float* p = in + i*8;
    float4 a = *(const float4*)p;
    float4 b = *(const float4*)(p+4);
    short8 v;
    v[0]=(short)f2bf(a.x); v[1]=(short)f2bf(a.y); v[2]=(short)f2bf(a.z); v[3]=(short)f2bf(a.w);
    v[4]=(short)f2bf(b.x); v[5]=(short)f2bf(b.y); v[6]=(short)f2bf(b.z); v[7]=(short)f2bf(b.w);
    *(short8*)(out + i*8) = v;
  }
}

__global__ void bias_combine(const float* __restrict__ a, const float* __restrict__ b, float* __restrict__ o,
                             const float* __restrict__ c, const float* __restrict__ d, float* __restrict__ p){
  int i = blockIdx.x * blockDim.x + threadIdx.x;
  if (i < Hn){ o[i] = a[i] + b[i]; p[i] = c[i] + d[i]; }
}

// ---------------- pre0 GEMM: C[t*Bn+b][n] = sum_k x[b*Tn+t][k]*Wih0[n][k] + bias[n] ----------
__launch_bounds__(256, 2)
__global__ void gemm_pre0(const float* __restrict__ Av, const unsigned short* __restrict__ Bm,
                          const float* __restrict__ bias, unsigned short* __restrict__ C,
                          int N, int K)
{
  __shared__ unsigned short lA[128*64];
  __shared__ unsigned short lB[128*64];
  int bn = blockIdx.x, bm = blockIdx.y;
  int m0 = bm*128, n0 = bn*128;
  int tid = threadIdx.x, lane = tid & 63, w = tid >> 6;
  int wm = (w >> 1)*64, wn = (w & 1)*64;
  int cl = lane & 15, kh = lane >> 4;

  f32x4 acc[4][4];
  f32x4 z = {0.f,0.f,0.f,0.f};
#pragma unroll
  for (int i=0;i<4;i++)
#pragma unroll
    for (int j=0;j<4;j++) acc[i][j]=z;

  for (int k0 = 0; k0 < K; k0 += 64){
    __syncthreads();
#pragma unroll
    for (int r = 0; r < 4; ++r){
      int c = r*256 + tid;
      int row = c >> 3, cof = (c & 7)*8;
      const float* ap = Av + (size_t)(m0+row)*K + k0 + cof;
      float4 a = *(const float4*)ap;
      float4 b = *(const float4*)(ap+4);
      short8 v;
      v[0]=(short)f2bf(a.x); v[1]=(short)f2bf(a.y); v[2]=(short)f2bf(a.z); v[3]=(short)f2bf(a.w);
      v[4]=(short)f2bf(b.x); v[5]=(short)f2bf(b.y); v[6]=(short)f2bf(b.z); v[7]=(short)f2bf(b.w);
      *(short8*)&lA[row*64 + cof] = v;
      const unsigned short* bp = Bm + (size_t)(n0+row)*K + k0 + cof;
      *(short8*)&lB[row*64 + cof] = *(const short8*)bp;
    }
    __syncthreads();
#pragma unroll
    for (int kk = 0; kk < 2; ++kk){
      int kb = kk*32 + kh*8;
      short8 af[4], bfr[4];
#pragma unroll
      for (int i=0;i<4;i++) af[i]  = *(const short8*)&lA[(wm + i*16 + cl)*64 + kb];
#pragma unroll
      for (int j=0;j<4;j++) bfr[j] = *(const short8*)&lB[(wn + j*16 + cl)*64 + kb];
#pragma unroll
      for (int i=0;i<4;i++)
#pragma unroll
        for (int j=0;j<4;j++)
          acc[i][j] = __builtin_amdgcn_mfma_f32_16x16x32_bf16(af[i], bfr[j], acc[i][j], 0,0,0);
    }
  }
#pragma unroll
  for (int j=0;j<4;j++){
    int n = n0 + wn + j*16 + cl;
    float bs = bias[n];
#pragma unroll
    for (int i=0;i<4;i++){
      int mr = m0 + wm + i*16 + kh*4;
#pragma unroll
      for (int e=0;e<4;e++){
        int m = mr + e;                       // m = b*Tn + t
        int b = m >> 9, t = m & (Tn-1);
        C[((size_t)t*Bn + b)*N + n] = f2bf(acc[i][j][e] + bs);
      }
    }
  }
}

// ---------------- fused 3-stage recurrence ----------------
// 192 wgs, bx = sub*8 + g. group g = bx&7 (one XCD under round-robin); sub = bx>>3:
// role = sub>>3 (0:L0-rec, 1:pre1-GEMV, 2:L1-rec), slot = sub&7 -> cols [128*slot,+128).
// Group owns batches [8g,8g+8). All inter-wg tiles chunk-ordered: chunk c=(n>>3)*8+r
// (16B) = h[r][(n>>3)*8..+8]; slot s owns chunks [128s,128s+128) = contiguous 2KB.
template<bool FAST>
__device__ __forceinline__ void rnn_body(
    int role, int g, int slot, int tid, int w, int cl, int kh, int lrow, int n0,
    const unsigned short* pre0, unsigned short* h1buf,
    const float* bias1, unsigned short* roll1, unsigned short* roll2,
    unsigned int* FLA, unsigned int* FLB, unsigned int* FLC,
    const short8* wf, unsigned short* hl, unsigned short* outl)
{
  const char* lbase = (const char*)hl;
  unsigned int* myflag = (role == 0 ? FLA : role == 1 ? FLB : FLC) + slot;
  int ns = w*16 + cl;                                   // slice-relative column
  int obase = ((ns >> 3)*8 + kh*4)*8 + (ns & 7);        // outl short idx, j stride 8

  if (role == 0){
    for (int t = 0; t < Tn; ++t){
      float pv[4] = {0.f,0.f,0.f,0.f};
      if (kh < 2){                        // pre0 immutable this dispatch: plain cached loads
        const unsigned short* pp = pre0 + ((size_t)t*Bn + g*8 + kh*4)*Hn + n0 + cl;
#pragma unroll
        for (int j=0;j<4;j++) pv[j] = bf2f(pp[(size_t)j*Hn]);
      }
      if (t > 0){
        if (tid == 0) wait8<FAST>(FLA, (unsigned)t);
        __syncthreads();                                           // B1
        stage_lin<FAST>(h1buf + ((size_t)(t-1)*8 + g)*8192, hl, tid);
        __syncthreads();                                           // B2
      }
      f32x4 acc = {0.f,0.f,0.f,0.f};
      if (t > 0) acc = mfma_tile(lbase, wf, lrow, kh);
      if (kh < 2){
#pragma unroll
        for (int j=0;j<4;j++) outl[obase + j*8] = f2bf(tanh_fast(acc[j] + pv[j]));
      }
      __syncthreads();                                             // B3 (outl ready)
      unsigned short* tile = h1buf + ((size_t)t*8 + g)*8192;
      if (tid < 128) st16<FAST>(tile + slot*1024 + tid*8, *(const u32x4*)(outl + tid*8));
      asm volatile("s_waitcnt vmcnt(0)" ::: "memory");
      __syncthreads();                                             // B4 (slice at L2/L3)
      if (tid == 0) st_flag<FAST>(myflag, (unsigned)(t+1));
    }
  } else if (role == 1){
    float bs = bias1[n0 + cl];
    for (int t = 0; t < Tn; ++t){
      if (tid == 0) wait8_dual<FAST>(FLA, (unsigned)(t+1), FLC, t >= 4 ? (unsigned)(t-3) : 0u);
      __syncthreads();                                             // B1
      stage_lin<FAST>(h1buf + ((size_t)t*8 + g)*8192, hl, tid);
      __syncthreads();                                             // B2
      f32x4 acc = mfma_tile(lbase, wf, lrow, kh);
      if (kh < 2){
#pragma unroll
        for (int j=0;j<4;j++) outl[obase + j*8] = f2bf(acc[j] + bs);
      }
      __syncthreads();                                             // B3
      unsigned short* tile = roll1 + (size_t)(g*4 + (t&3))*8192;
      if (tid < 128) st16<FAST>(tile + slot*1024 + tid*8, *(const u32x4*)(outl + tid*8));
      asm volatile("s_waitcnt vmcnt(0)" ::: "memory");
      __syncthreads();                                             // B4
      if (tid == 0) st_flag<FAST>(myflag, (unsigned)(t+1));
    }
  } else {
    for (int t = 0; t < Tn; ++t){
      if (tid == 0) wait8_dual<FAST>(FLB, (unsigned)(t+1), FLC, (unsigned)t);
      __syncthreads();                                             // B1
      float pv[4] = {0.f,0.f,0.f,0.f};
      if (kh < 2)
        ld4_chunk<FAST>(roll1 + (size_t)(g*4 + (t&3))*8192 + slot*1024 + obase, pv);
      if (t > 0)
        stage_lin<FAST>(roll2 + (size_t)(g*2 + ((t-1)&1))*8192, hl, tid);
      __syncthreads();                                             // B2
      f32x4 acc = {0.f,0.f,0.f,0.f};
      if (t > 0) acc = mfma_tile(lbase, wf, lrow, kh);
      if (kh < 2){
#pragma unroll
        for (int j=0;j<4;j++) outl[obase + j*8] = f2bf(tanh_fast(acc[j] + pv[j]));
      }
      __syncthreads();                                             // B3
      unsigned short* tile = roll2 + (size_t)(g*2 + (t&1))*8192;
      if (tid < 128) st16<FAST>(tile + slot*1024 + tid*8, *(const u32x4*)(outl + tid*8));
      asm volatile("s_waitcnt vmcnt(0)" ::: "memory");
      __syncthreads();                                             // B4
      if (tid == 0) st_flag<FAST>(myflag, (unsigned)(t+1));
    }
  }
}

__launch_bounds__(512, 2)
__global__ void rnn_fused(const unsigned short* __restrict__ pre0,
                          unsigned short* __restrict__ h1buf,
                          const float* __restrict__ Whh0,
                          const float* __restrict__ Wih1,
                          const float* __restrict__ Whh1,
                          const float* __restrict__ bias1,
                          unsigned short* __restrict__ roll1,
                          unsigned short* __restrict__ roll2,
                          unsigned int* ctrs)
{
  __shared__ __align__(16) unsigned short hl[8192];    // 16KB staged tile (chunk order)
  __shared__ __align__(16) unsigned short outl[1024];  // 2KB producer transpose buffer
  __shared__ int s_fast;
  int bx = blockIdx.x;
  int g = bx & 7;
  int sub = bx >> 3;
  int role = sub >> 3, slot = sub & 7;
  int tid = threadIdx.x, lane = tid & 63, w = tid >> 6;
  int n0 = slot*128 + w*16;
  int cl = lane & 15, kh = lane >> 4, lrow = cl & 7;
  unsigned int* FLA = ctrs + (0*8 + g)*32;   // 128B-spaced flag lines, 8 words each
  unsigned int* FLB = ctrs + (1*8 + g)*32;
  unsigned int* FLC = ctrs + (2*8 + g)*32;
  unsigned int* arrive1 = ctrs + 768;
  unsigned int* badf    = ctrs + 772;
  unsigned int* arrive2 = ctrs + 776;

  // ---- one-time protocol self-test (replicates the production sequence exactly) ----
  if (tid == 0){
    int xcc;
    asm volatile("s_getreg_b32 %0, hwreg(HW_REG_XCC_ID)" : "=s"(xcc));
    unsigned int* testw = ctrs + 800 + g*32;
    unsigned int* armed = testw + 8;
    if (xcc != g)
      __hip_atomic_fetch_or(badf, 1u, __ATOMIC_RELAXED, __HIP_MEMORY_SCOPE_AGENT);
    // prime this CU's L1 with the (stale, zero) test lines via plain cached loads
    unsigned pr = *(volatile const unsigned*)testw + *(volatile const unsigned*)armed;
    asm volatile("" :: "v"(pr));
    __hip_atomic_fetch_add(arrive1, 1u, __ATOMIC_ACQ_REL, __HIP_MEMORY_SCOPE_AGENT);
    int t1 = 0;
    for (int i = 0; i < (1 << 20); ++i){
      if (__hip_atomic_load(arrive1, __ATOMIC_ACQUIRE, __HIP_MEMORY_SCOPE_AGENT) >= 192u){ t1 = 1; break; }
      __builtin_amdgcn_s_sleep(2);
    }
    if (!t1) __hip_atomic_fetch_or(badf, 1u, __ATOMIC_RELAXED, __HIP_MEMORY_SCOPE_AGENT);
    if (sub == 0){                      // producer wg of group g: data sc0 -> vmcnt -> flag sc0
      unsigned magic = 0xC0FFEE00u | (unsigned)g;
      asm volatile("global_store_dword %0, %1, off sc0\n\t"
                   "s_waitcnt vmcnt(0)\n\t"
                   "global_store_dword %2, %3, off sc0"
                   :: "v"(testw), "v"(magic), "v"(armed), "v"(1u) : "memory");
    }
    int ok = 0;
    for (int i = 0; i < (1 << 15); ++i){
      if (ld1_fast(armed) == 1u){ ok = (ld1_fast(testw) == (0xC0FFEE00u | (unsigned)g)); break; }
      if (i > 16) __builtin_amdgcn_s_sleep(1);
    }
    if (!ok) __hip_atomic_fetch_or(badf, 1u, __ATOMIC_RELAXED, __HIP_MEMORY_SCOPE_AGENT);
    __hip_atomic_fetch_add(arrive2, 1u, __ATOMIC_ACQ_REL, __HIP_MEMORY_SCOPE_AGENT);
    int t2 = 0;
    for (int i = 0; i < (1 << 20); ++i){
      if (__hip_atomic_load(arrive2, __ATOMIC_ACQUIRE, __HIP_MEMORY_SCOPE_AGENT) >= 192u){ t2 = 1; break; }
      __builtin_amdgcn_s_sleep(2);
    }
    unsigned bad = __hip_atomic_load(badf, __ATOMIC_ACQUIRE, __HIP_MEMORY_SCOPE_AGENT);
    s_fast = (t2 && bad == 0u) ? 1 : 0;
  }
  __syncthreads();
  const bool fast = (s_fast != 0);

  // Resident weight slice as MFMA B-fragments: lane holds W[n0+cl][kk*32+kh*8+0..7]
  const float* Wmat = (role == 0) ? Whh0 : (role == 1) ? Wih1 : Whh1;
  short8 wf[32];
  {
    const float* wr = Wmat + (size_t)(n0 + cl)*Hn + kh*8;
#pragma unroll
    for (int kk = 0; kk < 32; ++kk){
      float4 a = *(const float4*)(wr + kk*32);
      float4 b = *(const float4*)(wr + kk*32 + 4);
      short8 v;
      v[0]=(short)f2bf(a.x); v[1]=(short)f2bf(a.y); v[2]=(short)f2bf(a.z); v[3]=(short)f2bf(a.w);
      v[4]=(short)f2bf(b.x); v[5]=(short)f2bf(b.y); v[6]=(short)f2bf(b.z); v[7]=(short)f2bf(b.w);
      wf[kk] = v;
    }
  }

  if (fast)
    rnn_body<true >(role, g, slot, tid, w, cl, kh, lrow, n0, pre0, h1buf,
                    bias1, roll1, roll2, FLA, FLB, FLC, wf, hl, outl);
  else
    rnn_body<false>(role, g, slot, tid, w, cl, kh, lrow, n0, pre0, h1buf,
                    bias1, roll1, roll2, FLA, FLB, FLC, wf, hl, outl);
}

// ---------------- FC head: out[b][o] = h2[b][T-1][:] . Wfc[o][:] + bfc[o] ----------------
__global__ void fc_k(const unsigned short* __restrict__ roll2,
                     const float* __restrict__ Wfc, const float* __restrict__ bfc,
                     float* __restrict__ out)
{
  int gw = (blockIdx.x * blockDim.x + threadIdx.x) >> 6;
  int lane = threadIdx.x & 63;
  int b = gw >> 7, o = gw & 127;
  // h2(T-1): group b>>3, ring slot (T-1)&1==1, chunk-ordered tile
  const unsigned short* tile = roll2 + (size_t)((b>>3)*2 + 1)*8192;
  int r = b & 7;
  const float* wr = Wfc + (size_t)o*Hn;
  float s = 0.f;
  for (int k = lane; k < Hn; k += 64)
    s += bf2f(tile[((k>>3)*8 + r)*8 + (k&7)]) * wr[k];
#pragma unroll
  for (int off = 32; off > 0; off >>= 1) s += __shfl_down(s, off, 64);
  if (lane == 0) out[b*OUTn + o] = s + bfc[o];
}

// ---------------- host ----------------
extern "C" void kernel_launch(void* const* d_in, const int* in_sizes, int n_in,
                              void* d_out, int out_size, void* d_ws, size_t ws_size,
                              hipStream_t stream)
{
  const float* x    = (const float*)d_in[0];
  const float* Wih0 = (const float*)d_in[1];
  const float* Whh0 = (const float*)d_in[2];
  const float* bih0 = (const float*)d_in[3];
  const float* bhh0 = (const float*)d_in[4];
  const float* Wih1 = (const float*)d_in[5];
  const float* Whh1 = (const float*)d_in[6];
  const float* bih1 = (const float*)d_in[7];
  const float* bhh1 = (const float*)d_in[8];
  const float* Wfc  = (const float*)d_in[9];
  const float* bfc  = (const float*)d_in[10];
  float* out = (float*)d_out;

  // workspace layout (bf16 elements)
  unsigned short* bufP  = (unsigned short*)d_ws;                    // pre0 [T][B][H] row-major
  unsigned short* bufH1 = bufP  + (size_t)Bn*Tn*Hn;                 // h1 tiles [T][8], chunk order
  unsigned short* wih0b = bufH1 + (size_t)Tn*8*8192;                // 1MiB
  unsigned short* roll1 = wih0b + (size_t)Hn*DINn;                  // [8][4] tiles
  unsigned short* roll2 = roll1 + (size_t)8*4*8192;                 // [8][2] tiles
  float* bias0 = (float*)(roll2 + (size_t)8*2*8192);
  float* bias1 = bias0 + Hn;
  unsigned int* ctrs = (unsigned int*)(bias1 + Hn);                 // 2048 uints

  hipMemsetAsync(ctrs, 0, 2048*sizeof(unsigned int), stream);

  cvt_bf16x8<<<256, 256, 0, stream>>>(Wih0, wih0b, (long long)Hn*DINn/8);
  bias_combine<<<4, 256, 0, stream>>>(bih0, bhh0, bias0, bih1, bhh1, bias1);

  // pre0 = x @ Wih0^T + bias0, written as [T][B][H]
  dim3 g1(Hn/128, (Bn*Tn)/128);
  gemm_pre0<<<g1, 256, 0, stream>>>(x, wih0b, bias0, bufP, Hn, DINn);

  // fused L0-rec -> pre1-GEMV -> L1-rec pipeline (self-tested XCD-local L2 protocol)
  rnn_fused<<<192, 512, 0, stream>>>(bufP, bufH1, Whh0, Wih1, Whh1, bias1,
                                     roll1, roll2, ctrs);

  // FC head from h2(T-1) ring slot
  fc_k<<<2048, 256, 0, stream>>>(roll2, Wfc, bfc, out);
}

// Round 8
// 1422.523 us; speedup vs baseline: 4.4644x; 4.4644x over previous
//
#include <hip/hip_runtime.h>
#include <stdint.h>
#include <stddef.h>

// Problem dims
#define Bn   64
#define Tn   512
#define DINn 512
#define Hn   1024
#define OUTn 128

typedef __attribute__((ext_vector_type(4))) float f32x4;
typedef __attribute__((ext_vector_type(8))) short short8;
typedef __attribute__((ext_vector_type(4))) unsigned int u32x4;

__device__ __forceinline__ unsigned short f2bf(float f){
  unsigned int x = __builtin_bit_cast(unsigned int, f);
  x += 0x7fffu + ((x >> 16) & 1u);           // RNE (values bounded, no NaN/inf)
  return (unsigned short)(x >> 16);
}
__device__ __forceinline__ float bf2f(unsigned short u){
  return __builtin_bit_cast(float, (unsigned int)u << 16);
}
__device__ __forceinline__ float tanh_fast(float v){
  float e = __expf(2.0f * v);
  return 1.0f - 2.0f / (e + 1.0f);
}

// ---- primitives ----
// FAST: XCD-local. Data: sc0 stores/loads at within-dispatch-unique addresses (L1 can
//       never hold a stale copy: each address is read at most once per dispatch, and
//       dispatch start invalidates L1). Flags: L2 atomics (atomics execute at L2,
//       bypassing L1 entirely — no buffer_inv needed; r7 lesson).
// !FAST: sc0 sc1 (MALL) everywhere — r4-proven, placement-independent.
template<bool FAST>
__device__ __forceinline__ void st16(unsigned short* p, u32x4 v){
  if constexpr (FAST)
    asm volatile("global_store_dwordx4 %0, %1, off sc0" :: "v"(p), "v"(v) : "memory");
  else
    asm volatile("global_store_dwordx4 %0, %1, off sc0 sc1" :: "v"(p), "v"(v) : "memory");
}
// returning L2 atomic (sc0 = return old); the L1-proof "fresh read"
__device__ __forceinline__ unsigned atom_poll(unsigned int* p){
  unsigned old, zero = 0;
  asm volatile("global_atomic_add %0, %1, %2, off sc0\n\t"
               "s_waitcnt vmcnt(0)"
               : "=&v"(old) : "v"(p), "v"(zero) : "memory");
  return old;
}
__device__ __forceinline__ void atom_inc(unsigned int* p){
  unsigned one = 1;
  asm volatile("global_atomic_add %0, %1, off" :: "v"(p), "v"(one) : "memory");
}
__device__ __forceinline__ unsigned ld1_sc0(const unsigned int* p){
  unsigned v;
  asm volatile("global_load_dword %0, %1, off sc0\n\t"
               "s_waitcnt vmcnt(0)" : "=&v"(v) : "v"(p) : "memory");
  return v;
}
__device__ __forceinline__ unsigned umin4(u32x4 a){
  unsigned m0 = a[0] < a[1] ? a[0] : a[1];
  unsigned m1 = a[2] < a[3] ? a[2] : a[3];
  return m0 < m1 ? m0 : m1;
}
__device__ __forceinline__ unsigned ld_line8_slow(const unsigned int* p){
  u32x4 a, b;
  asm volatile("global_load_dwordx4 %0, %2, off sc0 sc1\n\t"
               "global_load_dwordx4 %1, %3, off sc0 sc1\n\t"
               "s_waitcnt vmcnt(0)"
               : "=&v"(a), "=&v"(b) : "v"(p), "v"(p + 4) : "memory");
  unsigned ma = umin4(a), mb = umin4(b);
  return ma < mb ? ma : mb;
}
// Bounded waits (tid0 only). Worst case returns late -> visibly wrong, never a hang.
template<bool FAST>
__device__ __forceinline__ void wait_one(unsigned int* fc, unsigned int* fl, unsigned wf8, unsigned wslow){
  if constexpr (FAST){
    if (!wf8) return;
    for (int i = 0; i < (1 << 16); ++i){
      if (atom_poll(fc) >= wf8) return;
      if (i > 32) __builtin_amdgcn_s_sleep(1);
    }
  } else {
    if (!wslow) return;
    for (int i = 0; i < (1 << 16); ++i){
      if (ld_line8_slow(fl) >= wslow) return;
      if (i > 16) __builtin_amdgcn_s_sleep(1);
    }
  }
}
template<bool FAST>
__device__ __forceinline__ void wait_dual(unsigned int* fc1, unsigned int* fl1, unsigned wf1, unsigned ws1,
                                          unsigned int* fc2, unsigned int* fl2, unsigned wf2, unsigned ws2){
  if constexpr (FAST){
    if (!wf2){ wait_one<true>(fc1, fl1, wf1, ws1); return; }
    for (int i = 0; i < (1 << 16); ++i){
      if (atom_poll(fc1) >= wf1 && atom_poll(fc2) >= wf2) return;
      if (i > 32) __builtin_amdgcn_s_sleep(1);
    }
  } else {
    if (!ws2){ wait_one<false>(fc1, fl1, wf1, ws1); return; }
    for (int i = 0; i < (1 << 16); ++i){
      if (ld_line8_slow(fl1) >= ws1 && ld_line8_slow(fl2) >= ws2) return;
      if (i > 16) __builtin_amdgcn_s_sleep(1);
    }
  }
}

// Linear 16KB tile copy global->LDS (tiles pre-permuted in chunk order).
template<bool FAST>
__device__ __forceinline__ void stage_lin(const unsigned short* base, unsigned short* hl, int tid){
  const unsigned short* p0 = base + (size_t)tid * 8;
  const unsigned short* p1 = p0 + 512 * 8;
  u32x4 v0, v1;
  if constexpr (FAST)
    asm volatile("global_load_dwordx4 %0, %2, off sc0\n\t"
                 "global_load_dwordx4 %1, %3, off sc0\n\t"
                 "s_waitcnt vmcnt(0)"
                 : "=&v"(v0), "=&v"(v1) : "v"(p0), "v"(p1) : "memory");
  else
    asm volatile("global_load_dwordx4 %0, %2, off sc0 sc1\n\t"
                 "global_load_dwordx4 %1, %3, off sc0 sc1\n\t"
                 "s_waitcnt vmcnt(0)"
                 : "=&v"(v0), "=&v"(v1) : "v"(p0), "v"(p1) : "memory");
  *(u32x4*)((char*)hl + tid * 16) = v0;
  *(u32x4*)((char*)hl + tid * 16 + 8192) = v1;
}
// 4 bf16 scalar loads, chunk-order row walk (stride 8 shorts)
template<bool FAST>
__device__ __forceinline__ void ld4_chunk(const unsigned short* p, float* pv){
  unsigned u0,u1,u2,u3;
  if constexpr (FAST)
    asm volatile("global_load_ushort %0, %4, off sc0\n\t"
                 "global_load_ushort %1, %5, off sc0\n\t"
                 "global_load_ushort %2, %6, off sc0\n\t"
                 "global_load_ushort %3, %7, off sc0\n\t"
                 "s_waitcnt vmcnt(0)"
                 : "=&v"(u0), "=&v"(u1), "=&v"(u2), "=&v"(u3)
                 : "v"(p), "v"(p + 8), "v"(p + 16), "v"(p + 24) : "memory");
  else
    asm volatile("global_load_ushort %0, %4, off sc0 sc1\n\t"
                 "global_load_ushort %1, %5, off sc0 sc1\n\t"
                 "global_load_ushort %2, %6, off sc0 sc1\n\t"
                 "global_load_ushort %3, %7, off sc0 sc1\n\t"
                 "s_waitcnt vmcnt(0)"
                 : "=&v"(u0), "=&v"(u1), "=&v"(u2), "=&v"(u3)
                 : "v"(p), "v"(p + 8), "v"(p + 16), "v"(p + 24) : "memory");
  pv[0] = bf2f((unsigned short)u0); pv[1] = bf2f((unsigned short)u1);
  pv[2] = bf2f((unsigned short)u2); pv[3] = bf2f((unsigned short)u3);
}

// MFMA sweep over K=1024 on chunk-ordered tile (conflict-free: per kk a wave reads
// 512 consecutive bytes).
__device__ __forceinline__ f32x4 mfma_tile(const char* lbase, const short8* wf, int lrow, int kh){
  f32x4 a0 = {0.f,0.f,0.f,0.f}, a1 = a0, a2 = a0, a3 = a0;
  int rb = kh * 128 + lrow * 16;
#pragma unroll
  for (int kk = 0; kk < 8; ++kk)
    a0 = __builtin_amdgcn_mfma_f32_16x16x32_bf16(*(const short8*)(lbase + kk*512 + rb), wf[kk], a0, 0,0,0);
#pragma unroll
  for (int kk = 8; kk < 16; ++kk)
    a1 = __builtin_amdgcn_mfma_f32_16x16x32_bf16(*(const short8*)(lbase + kk*512 + rb), wf[kk], a1, 0,0,0);
#pragma unroll
  for (int kk = 16; kk < 24; ++kk)
    a2 = __builtin_amdgcn_mfma_f32_16x16x32_bf16(*(const short8*)(lbase + kk*512 + rb), wf[kk], a2, 0,0,0);
#pragma unroll
  for (int kk = 24; kk < 32; ++kk)
    a3 = __builtin_amdgcn_mfma_f32_16x16x32_bf16(*(const short8*)(lbase + kk*512 + rb), wf[kk], a3, 0,0,0);
  return (a0 + a1) + (a2 + a3);
}

// ---------------- elementwise f32 -> bf16 ----------------
__global__ void cvt_bf16x8(const float* __restrict__ in, unsigned short* __restrict__ out,
                           long long n8){
  long long i = (long long)blockIdx.x * blockDim.x + threadIdx.x;
  long long stride = (long long)gridDim.x * blockDim.x;
  for (; i < n8; i += stride){
    const float* p = in + i*8;
    float4 a = *(const float4*)p;
    float4 b = *(const float4*)(p+4);
    short8 v;
    v[0]=(short)f2bf(a.x); v[1]=(short)f2bf(a.y); v[2]=(short)f2bf(a.z); v[3]=(short)f2bf(a.w);
    v[4]=(short)f2bf(b.x); v[5]=(short)f2bf(b.y); v[6]=(short)f2bf(b.z); v[7]=(short)f2bf(b.w);
    *(short8*)(out + i*8) = v;
  }
}

__global__ void bias_combine(const float* __restrict__ a, const float* __restrict__ b, float* __restrict__ o,
                             const float* __restrict__ c, const float* __restrict__ d, float* __restrict__ p){
  int i = blockIdx.x * blockDim.x + threadIdx.x;
  if (i < Hn){ o[i] = a[i] + b[i]; p[i] = c[i] + d[i]; }
}

// ---------------- pre0 GEMM: C[t*Bn+b][n] = sum_k x[b*Tn+t][k]*Wih0[n][k] + bias[n] ----------
__launch_bounds__(256, 2)
__global__ void gemm_pre0(const float* __restrict__ Av, const unsigned short* __restrict__ Bm,
                          const float* __restrict__ bias, unsigned short* __restrict__ C,
                          int N, int K)
{
  __shared__ unsigned short lA[128*64];
  __shared__ unsigned short lB[128*64];
  int bn = blockIdx.x, bm = blockIdx.y;
  int m0 = bm*128, n0 = bn*128;
  int tid = threadIdx.x, lane = tid & 63, w = tid >> 6;
  int wm = (w >> 1)*64, wn = (w & 1)*64;
  int cl = lane & 15, kh = lane >> 4;

  f32x4 acc[4][4];
  f32x4 z = {0.f,0.f,0.f,0.f};
#pragma unroll
  for (int i=0;i<4;i++)
#pragma unroll
    for (int j=0;j<4;j++) acc[i][j]=z;

  for (int k0 = 0; k0 < K; k0 += 64){
    __syncthreads();
#pragma unroll
    for (int r = 0; r < 4; ++r){
      int c = r*256 + tid;
      int row = c >> 3, cof = (c & 7)*8;
      const float* ap = Av + (size_t)(m0+row)*K + k0 + cof;
      float4 a = *(const float4*)ap;
      float4 b = *(const float4*)(ap+4);
      short8 v;
      v[0]=(short)f2bf(a.x); v[1]=(short)f2bf(a.y); v[2]=(short)f2bf(a.z); v[3]=(short)f2bf(a.w);
      v[4]=(short)f2bf(b.x); v[5]=(short)f2bf(b.y); v[6]=(short)f2bf(b.z); v[7]=(short)f2bf(b.w);
      *(short8*)&lA[row*64 + cof] = v;
      const unsigned short* bp = Bm + (size_t)(n0+row)*K + k0 + cof;
      *(short8*)&lB[row*64 + cof] = *(const short8*)bp;
    }
    __syncthreads();
#pragma unroll
    for (int kk = 0; kk < 2; ++kk){
      int kb = kk*32 + kh*8;
      short8 af[4], bfr[4];
#pragma unroll
      for (int i=0;i<4;i++) af[i]  = *(const short8*)&lA[(wm + i*16 + cl)*64 + kb];
#pragma unroll
      for (int j=0;j<4;j++) bfr[j] = *(const short8*)&lB[(wn + j*16 + cl)*64 + kb];
#pragma unroll
      for (int i=0;i<4;i++)
#pragma unroll
        for (int j=0;j<4;j++)
          acc[i][j] = __builtin_amdgcn_mfma_f32_16x16x32_bf16(af[i], bfr[j], acc[i][j], 0,0,0);
    }
  }
#pragma unroll
  for (int j=0;j<4;j++){
    int n = n0 + wn + j*16 + cl;
    float bs = bias[n];
#pragma unroll
    for (int i=0;i<4;i++){
      int mr = m0 + wm + i*16 + kh*4;
#pragma unroll
      for (int e=0;e<4;e++){
        int m = mr + e;                       // m = b*Tn + t
        int b = m >> 9, t = m & (Tn-1);
        C[((size_t)t*Bn + b)*N + n] = f2bf(acc[i][j][e] + bs);
      }
    }
  }
}

// ---------------- fused 3-stage recurrence ----------------
// 192 wgs, g = bx&7 (one XCD under round-robin, runtime-verified); sub = bx>>3:
// role = sub>>3 (0:L0-rec, 1:pre1-GEMV, 2:L1-rec), slot = sub&7 -> cols [128*slot,+128).
// Group owns batches [8g,8g+8). Chunk-ordered 16KB tiles: chunk c=(n>>3)*8+r holds
// h[r][(n>>3)*8..+8]. Unique-address aliasing (no within-dispatch reuse):
//   h1(t)   -> h1buf tile index t+2
//   pre1(t) -> h1buf tile index t      (dead h1(t-2) slot; ordering via flag chain)
//   h2(t)   -> pre0 slice t            (consumed by role0 before role2 writes)
template<bool FAST>
__device__ __forceinline__ void rnn_body(
    int role, int g, int slot, int tid, int w, int lane, int cl, int kh, int lrow,
    const unsigned short* pre0, unsigned short* bufP, unsigned short* h1buf,
    const float* bias1,
    unsigned int* FCA, unsigned int* FCB, unsigned int* FCC,
    unsigned int* FLA, unsigned int* FLB, unsigned int* FLC,
    const short8* wf, unsigned short* hl, unsigned short* outl)
{
  const char* lbase = (const char*)hl;
  int n0 = slot*128 + w*16;
  int olocal = w*128 + ((cl>>3)*8 + kh*4)*8 + (cl&7);    // j stride 8 shorts
  unsigned int* myFC = (role == 0) ? FCA : (role == 1) ? FCB : FCC;
  unsigned int* myFL = ((role == 0) ? FLA : (role == 1) ? FLB : FLC) + slot;

  for (int t = 0; t < Tn; ++t){
    float pv[4] = {0.f,0.f,0.f,0.f};
    if (role == 0 && kh < 2){            // prefetch pre0 (plain cached; slice immutable here)
      const unsigned short* pp = pre0 + ((size_t)t*Bn + g*8 + kh*4)*Hn + n0 + cl;
#pragma unroll
      for (int j=0;j<4;j++) pv[j] = bf2f(pp[(size_t)j*Hn]);
    }
    // ---- wait ----
    if (tid == 0){
      if (role == 0)      wait_one <FAST>(FCA, FLA, 8u*(unsigned)t, (unsigned)t);
      else if (role == 1) wait_one <FAST>(FCA, FLA, 8u*(unsigned)(t+1), (unsigned)(t+1));
      else                wait_dual<FAST>(FCB, FLB, 8u*(unsigned)(t+1), (unsigned)(t+1),
                                          FCC, FLC, 8u*(unsigned)t, (unsigned)t);
    }
    __syncthreads();                                               // B1
    // ---- stage / aux reads ----
    bool staged = true;
    if (role == 0){
      if (t > 0) stage_lin<FAST>(h1buf + ((size_t)(t+1)*8 + g)*8192, hl, tid);  // h1(t-1)
      else staged = false;
    } else if (role == 1){
      stage_lin<FAST>(h1buf + ((size_t)(t+2)*8 + g)*8192, hl, tid);             // h1(t)
    } else {
      if (kh < 2)
        ld4_chunk<FAST>(h1buf + ((size_t)t*8 + g)*8192 + slot*1024 + ((w*16+cl)>>3)*64 + kh*32 + (cl&7), pv); // pre1(t)
      if (t > 0) stage_lin<FAST>(bufP + ((size_t)(t-1)*Bn + g*8)*Hn, hl, tid);  // h2(t-1)
      else staged = false;
    }
    __syncthreads();                                               // B2
    // ---- compute ----
    f32x4 acc = {0.f,0.f,0.f,0.f};
    if (staged) acc = mfma_tile(lbase, wf, lrow, kh);
    // ---- transpose to wave-local LDS, vector-store tile slice ----
    if (kh < 2){
      float bs = (role == 1) ? bias1[n0 + cl] : 0.f;
#pragma unroll
      for (int j=0;j<4;j++){
        float v = acc[j] + pv[j] + bs;
        if (role != 1) v = tanh_fast(v);
        outl[olocal + j*8] = f2bf(v);
      }
    }
    // same-wave cross-lane via LDS: hardware DS ordering within wave; may-alias keeps order
    unsigned short* tile;
    if (role == 0)      tile = h1buf + ((size_t)(t+2)*8 + g)*8192;
    else if (role == 1) tile = h1buf + ((size_t)t*8 + g)*8192;
    else                tile = bufP + ((size_t)t*Bn + g*8)*Hn;
    if (lane < 16){
      u32x4 v = *(const u32x4*)(outl + w*128 + lane*8);
      st16<FAST>(tile + slot*1024 + (w*16 + lane)*8, v);
    }
    asm volatile("s_waitcnt vmcnt(0)" ::: "memory");
    __syncthreads();                                               // B3 (all stores at L2/L3)
    if (tid == 0){
      if constexpr (FAST) atom_inc(myFC);
      else asm volatile("global_store_dword %0, %1, off sc0 sc1" :: "v"(myFL), "v"((unsigned)(t+1)) : "memory");
    }
  }
}

__launch_bounds__(512, 2)
__global__ void rnn_fused(const unsigned short* __restrict__ pre0_ro,
                          unsigned short* __restrict__ bufP,
                          unsigned short* __restrict__ h1buf,
                          const float* __restrict__ Whh0,
                          const float* __restrict__ Wih1,
                          const float* __restrict__ Whh1,
                          const float* __restrict__ bias1,
                          unsigned int* ctrs)
{
  __shared__ __align__(16) unsigned short hl[8192];    // 16KB staged tile (chunk order)
  __shared__ __align__(16) unsigned short outl[1024];  // 2KB, wave-local transpose
  __shared__ int s_fast;
  int bx = blockIdx.x;
  int g = bx & 7;
  int sub = bx >> 3;
  int role = sub >> 3, slot = sub & 7;
  int tid = threadIdx.x, lane = tid & 63, w = tid >> 6;
  int n0 = slot*128 + w*16;
  int cl = lane & 15, kh = lane >> 4, lrow = cl & 7;
  unsigned int* FLA = ctrs + (0*8 + g)*32;   // slow-path flag lines (8 words each)
  unsigned int* FLB = ctrs + (1*8 + g)*32;
  unsigned int* FLC = ctrs + (2*8 + g)*32;
  unsigned int* arrive1 = ctrs + 768;
  unsigned int* badf    = ctrs + 772;
  unsigned int* arrive2 = ctrs + 776;
  unsigned int* FCA = ctrs + 1536 + (0*8 + g)*32;  // fast-path counters (128B-spaced)
  unsigned int* FCB = ctrs + 1536 + (1*8 + g)*32;
  unsigned int* FCC = ctrs + 1536 + (2*8 + g)*32;

  // ---- one-time self-test of the EXACT fast-path sequence ----
  if (tid == 0){
    int xcc;
    asm volatile("s_getreg_b32 %0, hwreg(HW_REG_XCC_ID)" : "=s"(xcc));
    unsigned int* testw = ctrs + 1024 + g*32;
    unsigned int* armed = testw + 16;
    if (xcc != g)
      __hip_atomic_fetch_or(badf, 1u, __ATOMIC_RELAXED, __HIP_MEMORY_SCOPE_AGENT);
    __hip_atomic_fetch_add(arrive1, 1u, __ATOMIC_ACQ_REL, __HIP_MEMORY_SCOPE_AGENT);
    int t1 = 0;
    for (int i = 0; i < (1 << 20); ++i){
      if (__hip_atomic_load(arrive1, __ATOMIC_ACQUIRE, __HIP_MEMORY_SCOPE_AGENT) >= 192u){ t1 = 1; break; }
      __builtin_amdgcn_s_sleep(2);
    }
    if (!t1) __hip_atomic_fetch_or(badf, 1u, __ATOMIC_RELAXED, __HIP_MEMORY_SCOPE_AGENT);
    unsigned magic = 0xC0FFEE00u | (unsigned)g;
    if (sub == 0){                      // producer: sc0 data -> vmcnt -> L2-atomic flag
      asm volatile("global_store_dword %0, %1, off sc0\n\t"
                   "s_waitcnt vmcnt(0)" :: "v"(testw), "v"(magic) : "memory");
      atom_inc(armed);
    }
    int ok = 0;
    for (int i = 0; i < (1 << 15); ++i){
      if (atom_poll(armed) >= 1u){ ok = (ld1_sc0(testw) == magic); break; }
      if (i > 16) __builtin_amdgcn_s_sleep(1);
    }
    if (!ok) __hip_atomic_fetch_or(badf, 1u, __ATOMIC_RELAXED, __HIP_MEMORY_SCOPE_AGENT);
    __hip_atomic_fetch_add(arrive2, 1u, __ATOMIC_ACQ_REL, __HIP_MEMORY_SCOPE_AGENT);
    int t2 = 0;
    for (int i = 0; i < (1 << 20); ++i){
      if (__hip_atomic_load(arrive2, __ATOMIC_ACQUIRE, __HIP_MEMORY_SCOPE_AGENT) >= 192u){ t2 = 1; break; }
      __builtin_amdgcn_s_sleep(2);
    }
    unsigned bad = __hip_atomic_load(badf, __ATOMIC_ACQUIRE, __HIP_MEMORY_SCOPE_AGENT);
    s_fast = (t2 && bad == 0u) ? 1 : 0;
  }
  __syncthreads();
  const bool fast = (s_fast != 0);

  // Resident weight slice as MFMA B-fragments: lane holds W[n0+cl][kk*32+kh*8+0..7]
  const float* Wmat = (role == 0) ? Whh0 : (role == 1) ? Wih1 : Whh1;
  short8 wf[32];
  {
    const float* wr = Wmat + (size_t)(n0 + cl)*Hn + kh*8;
#pragma unroll
    for (int kk = 0; kk < 32; ++kk){
      float4 a = *(const float4*)(wr + kk*32);
      float4 b = *(const float4*)(wr + kk*32 + 4);
      short8 v;
      v[0]=(short)f2bf(a.x); v[1]=(short)f2bf(a.y); v[2]=(short)f2bf(a.z); v[3]=(short)f2bf(a.w);
      v[4]=(short)f2bf(b.x); v[5]=(short)f2bf(b.y); v[6]=(short)f2bf(b.z); v[7]=(short)f2bf(b.w);
      wf[kk] = v;
    }
  }

  if (fast)
    rnn_body<true >(role, g, slot, tid, w, lane, cl, kh, lrow, pre0_ro, bufP, h1buf,
                    bias1, FCA, FCB, FCC, FLA, FLB, FLC, wf, hl, outl);
  else
    rnn_body<false>(role, g, slot, tid, w, lane, cl, kh, lrow, pre0_ro, bufP, h1buf,
                    bias1, FCA, FCB, FCC, FLA, FLB, FLC, wf, hl, outl);
}

// ---------------- FC head: out[b][o] = h2[b][T-1][:] . Wfc[o][:] + bfc[o] ----------------
__global__ void fc_k(const unsigned short* __restrict__ bufP,
                     const float* __restrict__ Wfc, const float* __restrict__ bfc,
                     float* __restrict__ out)
{
  int gw = (blockIdx.x * blockDim.x + threadIdx.x) >> 6;
  int lane = threadIdx.x & 63;
  int b = gw >> 7, o = gw & 127;
  // h2(T-1) lives in pre0 slice T-1, group tile (b>>3), chunk-ordered
  const unsigned short* tile = bufP + ((size_t)(Tn-1)*Bn + (b & ~7))*Hn;
  int r = b & 7;
  const float* wr = Wfc + (size_t)o*Hn;
  float s = 0.f;
  for (int k = lane; k < Hn; k += 64)
    s += bf2f(tile[((k>>3)*8 + r)*8 + (k&7)]) * wr[k];
#pragma unroll
  for (int off = 32; off > 0; off >>= 1) s += __shfl_down(s, off, 64);
  if (lane == 0) out[b*OUTn + o] = s + bfc[o];
}

// ---------------- host ----------------
extern "C" void kernel_launch(void* const* d_in, const int* in_sizes, int n_in,
                              void* d_out, int out_size, void* d_ws, size_t ws_size,
                              hipStream_t stream)
{
  const float* x    = (const float*)d_in[0];
  const float* Wih0 = (const float*)d_in[1];
  const float* Whh0 = (const float*)d_in[2];
  const float* bih0 = (const float*)d_in[3];
  const float* bhh0 = (const float*)d_in[4];
  const float* Wih1 = (const float*)d_in[5];
  const float* Whh1 = (const float*)d_in[6];
  const float* bih1 = (const float*)d_in[7];
  const float* bhh1 = (const float*)d_in[8];
  const float* Wfc  = (const float*)d_in[9];
  const float* bfc  = (const float*)d_in[10];
  float* out = (float*)d_out;

  // workspace (bf16 elements)
  unsigned short* bufP  = (unsigned short*)d_ws;                    // pre0 [T][B][H]; h2 aliases slices
  unsigned short* h1buf = bufP  + (size_t)Bn*Tn*Hn;                 // (T+2)*8 chunk-ordered 16KB tiles
  unsigned short* wih0b = h1buf + (size_t)(Tn+2)*8*8192;            // 1MiB
  float* bias0 = (float*)(wih0b + (size_t)Hn*DINn);
  float* bias1 = bias0 + Hn;
  unsigned int* ctrs = (unsigned int*)(bias1 + Hn);                 // 4096 uints

  hipMemsetAsync(ctrs, 0, 4096*sizeof(unsigned int), stream);

  cvt_bf16x8<<<256, 256, 0, stream>>>(Wih0, wih0b, (long long)Hn*DINn/8);
  bias_combine<<<4, 256, 0, stream>>>(bih0, bhh0, bias0, bih1, bhh1, bias1);

  // pre0 = x @ Wih0^T + bias0, written as [T][B][H]
  dim3 g1(Hn/128, (Bn*Tn)/128);
  gemm_pre0<<<g1, 256, 0, stream>>>(x, wih0b, bias0, bufP, Hn, DINn);

  // fused L0-rec -> pre1-GEMV -> L1-rec pipeline (self-tested XCD-local L2 protocol)
  rnn_fused<<<192, 512, 0, stream>>>(bufP, bufP, h1buf, Whh0, Wih1, Whh1, bias1, ctrs);

  // FC head from h2(T-1) (aliased into pre0 slice T-1)
  fc_k<<<2048, 256, 0, stream>>>(bufP, Wfc, bfc, out);
}

// Round 9
// 1383.799 us; speedup vs baseline: 4.5893x; 1.0280x over previous
//
#include <hip/hip_runtime.h>
#include <stdint.h>
#include <stddef.h>

// Problem dims
#define Bn   64
#define Tn   512
#define DINn 512
#define Hn   1024
#define OUTn 128

typedef __attribute__((ext_vector_type(4))) float f32x4;
typedef __attribute__((ext_vector_type(8))) short short8;
typedef __attribute__((ext_vector_type(4))) unsigned int u32x4;

__device__ __forceinline__ unsigned short f2bf(float f){
  unsigned int x = __builtin_bit_cast(unsigned int, f);
  x += 0x7fffu + ((x >> 16) & 1u);           // RNE (values bounded, no NaN/inf)
  return (unsigned short)(x >> 16);
}
__device__ __forceinline__ float bf2f(unsigned short u){
  return __builtin_bit_cast(float, (unsigned int)u << 16);
}
__device__ __forceinline__ float tanh_fast(float v){
  float e = __expf(2.0f * v);
  return 1.0f - 2.0f / (e + 1.0f);
}

// ---- primitives ----
// FAST: XCD-local. Data: sc0 stores/loads at within-dispatch-unique addresses (L1 can
//       never hold a stale copy). Flags: L2 atomics (execute at L2, bypass L1; r7 lesson).
//       Flag lines are split per consumer role to cut same-line RMW contention (r8 lesson).
// !FAST: sc0 sc1 (MALL) everywhere — r4-proven, placement-independent.
template<bool FAST>
__device__ __forceinline__ void st16(unsigned short* p, u32x4 v){
  if constexpr (FAST)
    asm volatile("global_store_dwordx4 %0, %1, off sc0" :: "v"(p), "v"(v) : "memory");
  else
    asm volatile("global_store_dwordx4 %0, %1, off sc0 sc1" :: "v"(p), "v"(v) : "memory");
}
// returning L2 atomic (sc0 = return old); the L1-proof "fresh read"
__device__ __forceinline__ unsigned atom_poll(unsigned int* p){
  unsigned old, zero = 0;
  asm volatile("global_atomic_add %0, %1, %2, off sc0\n\t"
               "s_waitcnt vmcnt(0)"
               : "=&v"(old) : "v"(p), "v"(zero) : "memory");
  return old;
}
// two returning atomics issued back-to-back, single drain (halves dual-wait latency)
__device__ __forceinline__ void atom_poll2(unsigned int* p1, unsigned int* p2,
                                           unsigned &v1, unsigned &v2){
  unsigned zero = 0;
  asm volatile("global_atomic_add %0, %2, %4, off sc0\n\t"
               "global_atomic_add %1, %3, %4, off sc0\n\t"
               "s_waitcnt vmcnt(0)"
               : "=&v"(v1), "=&v"(v2)
               : "v"(p1), "v"(p2), "v"(zero) : "memory");
}
__device__ __forceinline__ void atom_inc(unsigned int* p){
  unsigned one = 1;
  asm volatile("global_atomic_add %0, %1, off" :: "v"(p), "v"(one) : "memory");
}
__device__ __forceinline__ unsigned ld1_sc0(const unsigned int* p){
  unsigned v;
  asm volatile("global_load_dword %0, %1, off sc0\n\t"
               "s_waitcnt vmcnt(0)" : "=&v"(v) : "v"(p) : "memory");
  return v;
}
__device__ __forceinline__ unsigned umin4(u32x4 a){
  unsigned m0 = a[0] < a[1] ? a[0] : a[1];
  unsigned m1 = a[2] < a[3] ? a[2] : a[3];
  return m0 < m1 ? m0 : m1;
}
__device__ __forceinline__ unsigned ld_line8_slow(const unsigned int* p){
  u32x4 a, b;
  asm volatile("global_load_dwordx4 %0, %2, off sc0 sc1\n\t"
               "global_load_dwordx4 %1, %3, off sc0 sc1\n\t"
               "s_waitcnt vmcnt(0)"
               : "=&v"(a), "=&v"(b) : "v"(p), "v"(p + 4) : "memory");
  unsigned ma = umin4(a), mb = umin4(b);
  return ma < mb ? ma : mb;
}
// Bounded waits (tid0 only). Worst case returns late -> visibly wrong, never a hang.
template<bool FAST>
__device__ __forceinline__ void wait_one(unsigned int* fc, unsigned int* fl, unsigned wf8, unsigned wslow){
  if constexpr (FAST){
    if (!wf8) return;
    for (int i = 0; i < (1 << 16); ++i){
      if (atom_poll(fc) >= wf8) return;
      __builtin_amdgcn_s_sleep(2);                 // pace pollers: cut L2 RMW contention
    }
  } else {
    if (!wslow) return;
    for (int i = 0; i < (1 << 16); ++i){
      if (ld_line8_slow(fl) >= wslow) return;
      if (i > 16) __builtin_amdgcn_s_sleep(1);
    }
  }
}
template<bool FAST>
__device__ __forceinline__ void wait_dual(unsigned int* fc1, unsigned int* fl1, unsigned wf1, unsigned ws1,
                                          unsigned int* fc2, unsigned int* fl2, unsigned wf2, unsigned ws2){
  if constexpr (FAST){
    if (!wf2){ wait_one<true>(fc1, fl1, wf1, ws1); return; }
    for (int i = 0; i < (1 << 16); ++i){
      unsigned v1, v2;
      atom_poll2(fc1, fc2, v1, v2);
      if (v1 >= wf1 && v2 >= wf2) return;
      __builtin_amdgcn_s_sleep(2);
    }
  } else {
    if (!ws2){ wait_one<false>(fc1, fl1, wf1, ws1); return; }
    for (int i = 0; i < (1 << 16); ++i){
      if (ld_line8_slow(fl1) >= ws1 && ld_line8_slow(fl2) >= ws2) return;
      if (i > 16) __builtin_amdgcn_s_sleep(1);
    }
  }
}

// Linear 16KB tile copy global->LDS (tiles pre-permuted in chunk order).
template<bool FAST>
__device__ __forceinline__ void stage_lin(const unsigned short* base, unsigned short* hl, int tid){
  const unsigned short* p0 = base + (size_t)tid * 8;
  const unsigned short* p1 = p0 + 512 * 8;
  u32x4 v0, v1;
  if constexpr (FAST)
    asm volatile("global_load_dwordx4 %0, %2, off sc0\n\t"
                 "global_load_dwordx4 %1, %3, off sc0\n\t"
                 "s_waitcnt vmcnt(0)"
                 : "=&v"(v0), "=&v"(v1) : "v"(p0), "v"(p1) : "memory");
  else
    asm volatile("global_load_dwordx4 %0, %2, off sc0 sc1\n\t"
                 "global_load_dwordx4 %1, %3, off sc0 sc1\n\t"
                 "s_waitcnt vmcnt(0)"
                 : "=&v"(v0), "=&v"(v1) : "v"(p0), "v"(p1) : "memory");
  *(u32x4*)((char*)hl + tid * 16) = v0;
  *(u32x4*)((char*)hl + tid * 16 + 8192) = v1;
}
// 4 bf16 scalar loads, chunk-order row walk (stride 8 shorts)
template<bool FAST>
__device__ __forceinline__ void ld4_chunk(const unsigned short* p, float* pv){
  unsigned u0,u1,u2,u3;
  if constexpr (FAST)
    asm volatile("global_load_ushort %0, %4, off sc0\n\t"
                 "global_load_ushort %1, %5, off sc0\n\t"
                 "global_load_ushort %2, %6, off sc0\n\t"
                 "global_load_ushort %3, %7, off sc0\n\t"
                 "s_waitcnt vmcnt(0)"
                 : "=&v"(u0), "=&v"(u1), "=&v"(u2), "=&v"(u3)
                 : "v"(p), "v"(p + 8), "v"(p + 16), "v"(p + 24) : "memory");
  else
    asm volatile("global_load_ushort %0, %4, off sc0 sc1\n\t"
                 "global_load_ushort %1, %5, off sc0 sc1\n\t"
                 "global_load_ushort %2, %6, off sc0 sc1\n\t"
                 "global_load_ushort %3, %7, off sc0 sc1\n\t"
                 "s_waitcnt vmcnt(0)"
                 : "=&v"(u0), "=&v"(u1), "=&v"(u2), "=&v"(u3)
                 : "v"(p), "v"(p + 8), "v"(p + 16), "v"(p + 24) : "memory");
  pv[0] = bf2f((unsigned short)u0); pv[1] = bf2f((unsigned short)u1);
  pv[2] = bf2f((unsigned short)u2); pv[3] = bf2f((unsigned short)u3);
}

// MFMA sweep over K=1024 on chunk-ordered tile (conflict-free: per kk a wave reads
// 512 consecutive bytes).
__device__ __forceinline__ f32x4 mfma_tile(const char* lbase, const short8* wf, int lrow, int kh){
  f32x4 a0 = {0.f,0.f,0.f,0.f}, a1 = a0, a2 = a0, a3 = a0;
  int rb = kh * 128 + lrow * 16;
#pragma unroll
  for (int kk = 0; kk < 8; ++kk)
    a0 = __builtin_amdgcn_mfma_f32_16x16x32_bf16(*(const short8*)(lbase + kk*512 + rb), wf[kk], a0, 0,0,0);
#pragma unroll
  for (int kk = 8; kk < 16; ++kk)
    a1 = __builtin_amdgcn_mfma_f32_16x16x32_bf16(*(const short8*)(lbase + kk*512 + rb), wf[kk], a1, 0,0,0);
#pragma unroll
  for (int kk = 16; kk < 24; ++kk)
    a2 = __builtin_amdgcn_mfma_f32_16x16x32_bf16(*(const short8*)(lbase + kk*512 + rb), wf[kk], a2, 0,0,0);
#pragma unroll
  for (int kk = 24; kk < 32; ++kk)
    a3 = __builtin_amdgcn_mfma_f32_16x16x32_bf16(*(const short8*)(lbase + kk*512 + rb), wf[kk], a3, 0,0,0);
  return (a0 + a1) + (a2 + a3);
}

// ---------------- elementwise f32 -> bf16 ----------------
__global__ void cvt_bf16x8(const float* __restrict__ in, unsigned short* __restrict__ out,
                           long long n8){
  long long i = (long long)blockIdx.x * blockDim.x + threadIdx.x;
  long long stride = (long long)gridDim.x * blockDim.x;
  for (; i < n8; i += stride){
    const float* p = in + i*8;
    float4 a = *(const float4*)p;
    float4 b = *(const float4*)(p+4);
    short8 v;
    v[0]=(short)f2bf(a.x); v[1]=(short)f2bf(a.y); v[2]=(short)f2bf(a.z); v[3]=(short)f2bf(a.w);
    v[4]=(short)f2bf(b.x); v[5]=(short)f2bf(b.y); v[6]=(short)f2bf(b.z); v[7]=(short)f2bf(b.w);
    *(short8*)(out + i*8) = v;
  }
}

__global__ void bias_combine(const float* __restrict__ a, const float* __restrict__ b, float* __restrict__ o,
                             const float* __restrict__ c, const float* __restrict__ d, float* __restrict__ p){
  int i = blockIdx.x * blockDim.x + threadIdx.x;
  if (i < Hn){ o[i] = a[i] + b[i]; p[i] = c[i] + d[i]; }
}

// ---------------- pre0 GEMM: C[t*Bn+b][n] = sum_k x[b*Tn+t][k]*Wih0[n][k] + bias[n] ----------
__launch_bounds__(256, 2)
__global__ void gemm_pre0(const float* __restrict__ Av, const unsigned short* __restrict__ Bm,
                          const float* __restrict__ bias, unsigned short* __restrict__ C,
                          int N, int K)
{
  __shared__ unsigned short lA[128*64];
  __shared__ unsigned short lB[128*64];
  int bn = blockIdx.x, bm = blockIdx.y;
  int m0 = bm*128, n0 = bn*128;
  int tid = threadIdx.x, lane = tid & 63, w = tid >> 6;
  int wm = (w >> 1)*64, wn = (w & 1)*64;
  int cl = lane & 15, kh = lane >> 4;

  f32x4 acc[4][4];
  f32x4 z = {0.f,0.f,0.f,0.f};
#pragma unroll
  for (int i=0;i<4;i++)
#pragma unroll
    for (int j=0;j<4;j++) acc[i][j]=z;

  for (int k0 = 0; k0 < K; k0 += 64){
    __syncthreads();
#pragma unroll
    for (int r = 0; r < 4; ++r){
      int c = r*256 + tid;
      int row = c >> 3, cof = (c & 7)*8;
      const float* ap = Av + (size_t)(m0+row)*K + k0 + cof;
      float4 a = *(const float4*)ap;
      float4 b = *(const float4*)(ap+4);
      short8 v;
      v[0]=(short)f2bf(a.x); v[1]=(short)f2bf(a.y); v[2]=(short)f2bf(a.z); v[3]=(short)f2bf(a.w);
      v[4]=(short)f2bf(b.x); v[5]=(short)f2bf(b.y); v[6]=(short)f2bf(b.z); v[7]=(short)f2bf(b.w);
      *(short8*)&lA[row*64 + cof] = v;
      const unsigned short* bp = Bm + (size_t)(n0+row)*K + k0 + cof;
      *(short8*)&lB[row*64 + cof] = *(const short8*)bp;
    }
    __syncthreads();
#pragma unroll
    for (int kk = 0; kk < 2; ++kk){
      int kb = kk*32 + kh*8;
      short8 af[4], bfr[4];
#pragma unroll
      for (int i=0;i<4;i++) af[i]  = *(const short8*)&lA[(wm + i*16 + cl)*64 + kb];
#pragma unroll
      for (int j=0;j<4;j++) bfr[j] = *(const short8*)&lB[(wn + j*16 + cl)*64 + kb];
#pragma unroll
      for (int i=0;i<4;i++)
#pragma unroll
        for (int j=0;j<4;j++)
          acc[i][j] = __builtin_amdgcn_mfma_f32_16x16x32_bf16(af[i], bfr[j], acc[i][j], 0,0,0);
    }
  }
#pragma unroll
  for (int j=0;j<4;j++){
    int n = n0 + wn + j*16 + cl;
    float bs = bias[n];
#pragma unroll
    for (int i=0;i<4;i++){
      int mr = m0 + wm + i*16 + kh*4;
#pragma unroll
      for (int e=0;e<4;e++){
        int m = mr + e;                       // m = b*Tn + t
        int b = m >> 9, t = m & (Tn-1);
        C[((size_t)t*Bn + b)*N + n] = f2bf(acc[i][j][e] + bs);
      }
    }
  }
}

// ---------------- fused 3-stage recurrence ----------------
// 192 wgs, g = bx&7 (one XCD under round-robin, runtime-verified); sub = bx>>3:
// role = sub>>3 (0:L0-rec, 1:pre1-GEMV, 2:L1-rec), slot = sub&7 -> cols [128*slot,+128).
// Group owns batches [8g,8g+8). Chunk-ordered 16KB tiles: chunk c=(n>>3)*8+r holds
// h[r][(n>>3)*8..+8]. Unique-address aliasing (no within-dispatch reuse):
//   h1(t)   -> h1buf tile index t+2
//   pre1(t) -> h1buf tile index t      (dead h1(t-2) slot; ordering via flag chain)
//   h2(t)   -> pre0 slice t            (consumed by role0 before role2 writes)
// Flag counters (FAST), split per consumer role: role0 increments FCA0 (polled by
// role0 self-sync) AND FCA1 (polled by role1); role1 -> FCB (role2); role2 -> FCC (role2).
template<bool FAST>
__device__ __forceinline__ void rnn_body(
    int role, int g, int slot, int tid, int w, int lane, int cl, int kh, int lrow,
    const unsigned short* pre0, unsigned short* bufP, unsigned short* h1buf,
    const float* bias1,
    unsigned int* FCA0, unsigned int* FCA1, unsigned int* FCB, unsigned int* FCC,
    unsigned int* FLA, unsigned int* FLB, unsigned int* FLC,
    const short8* wf, unsigned short* hl, unsigned short* outl)
{
  const char* lbase = (const char*)hl;
  int n0 = slot*128 + w*16;
  int olocal = w*128 + ((cl>>3)*8 + kh*4)*8 + (cl&7);    // j stride 8 shorts
  unsigned int* myFL = ((role == 0) ? FLA : (role == 1) ? FLB : FLC) + slot;

  for (int t = 0; t < Tn; ++t){
    float pv[4] = {0.f,0.f,0.f,0.f};
    if (role == 0 && kh < 2){            // prefetch pre0 (plain cached; slice immutable here)
      const unsigned short* pp = pre0 + ((size_t)t*Bn + g*8 + kh*4)*Hn + n0 + cl;
#pragma unroll
      for (int j=0;j<4;j++) pv[j] = bf2f(pp[(size_t)j*Hn]);
    }
    // ---- wait ----
    if (tid == 0){
      if (role == 0)      wait_one <FAST>(FCA0, FLA, 8u*(unsigned)t, (unsigned)t);
      else if (role == 1) wait_one <FAST>(FCA1, FLA, 8u*(unsigned)(t+1), (unsigned)(t+1));
      else                wait_dual<FAST>(FCB, FLB, 8u*(unsigned)(t+1), (unsigned)(t+1),
                                          FCC, FLC, 8u*(unsigned)t, (unsigned)t);
    }
    __syncthreads();                                               // B1
    // ---- stage / aux reads ----
    bool staged = true;
    if (role == 0){
      if (t > 0) stage_lin<FAST>(h1buf + ((size_t)(t+1)*8 + g)*8192, hl, tid);  // h1(t-1)
      else staged = false;
    } else if (role == 1){
      stage_lin<FAST>(h1buf + ((size_t)(t+2)*8 + g)*8192, hl, tid);             // h1(t)
    } else {
      if (kh < 2)
        ld4_chunk<FAST>(h1buf + ((size_t)t*8 + g)*8192 + slot*1024 + ((w*16+cl)>>3)*64 + kh*32 + (cl&7), pv); // pre1(t)
      if (t > 0) stage_lin<FAST>(bufP + ((size_t)(t-1)*Bn + g*8)*Hn, hl, tid);  // h2(t-1)
      else staged = false;
    }
    __syncthreads();                                               // B2
    // ---- compute ----
    f32x4 acc = {0.f,0.f,0.f,0.f};
    if (staged) acc = mfma_tile(lbase, wf, lrow, kh);
    // ---- transpose to wave-local LDS, vector-store tile slice ----
    if (kh < 2){
      float bs = (role == 1) ? bias1[n0 + cl] : 0.f;
#pragma unroll
      for (int j=0;j<4;j++){
        float v = acc[j] + pv[j] + bs;
        if (role != 1) v = tanh_fast(v);
        outl[olocal + j*8] = f2bf(v);
      }
    }
    // same-wave cross-lane via LDS: hardware DS ordering within wave
    unsigned short* tile;
    if (role == 0)      tile = h1buf + ((size_t)(t+2)*8 + g)*8192;
    else if (role == 1) tile = h1buf + ((size_t)t*8 + g)*8192;
    else                tile = bufP + ((size_t)t*Bn + g*8)*Hn;
    if (lane < 16){
      u32x4 v = *(const u32x4*)(outl + w*128 + lane*8);
      st16<FAST>(tile + slot*1024 + (w*16 + lane)*8, v);
    }
    asm volatile("s_waitcnt vmcnt(0)" ::: "memory");
    __syncthreads();                                               // B3 (all stores at L2/L3)
    if (tid == 0){
      if constexpr (FAST){
        if (role == 0){ atom_inc(FCA0); atom_inc(FCA1); }
        else if (role == 1) atom_inc(FCB);
        else atom_inc(FCC);
      } else {
        asm volatile("global_store_dword %0, %1, off sc0 sc1" :: "v"(myFL), "v"((unsigned)(t+1)) : "memory");
      }
    }
  }
}

__launch_bounds__(512, 2)
__global__ void rnn_fused(const unsigned short* __restrict__ pre0_ro,
                          unsigned short* __restrict__ bufP,
                          unsigned short* __restrict__ h1buf,
                          const float* __restrict__ Whh0,
                          const float* __restrict__ Wih1,
                          const float* __restrict__ Whh1,
                          const float* __restrict__ bias1,
                          unsigned int* ctrs)
{
  __shared__ __align__(16) unsigned short hl[8192];    // 16KB staged tile (chunk order)
  __shared__ __align__(16) unsigned short outl[1024];  // 2KB, wave-local transpose
  __shared__ int s_fast;
  int bx = blockIdx.x;
  int g = bx & 7;
  int sub = bx >> 3;
  int role = sub >> 3, slot = sub & 7;
  int tid = threadIdx.x, lane = tid & 63, w = tid >> 6;
  int n0 = slot*128 + w*16;
  int cl = lane & 15, kh = lane >> 4, lrow = cl & 7;
  unsigned int* FLA = ctrs + (0*8 + g)*32;   // slow-path flag lines (8 words each)
  unsigned int* FLB = ctrs + (1*8 + g)*32;
  unsigned int* FLC = ctrs + (2*8 + g)*32;
  unsigned int* arrive1 = ctrs + 768;
  unsigned int* badf    = ctrs + 772;
  unsigned int* arrive2 = ctrs + 776;
  unsigned int* FCA0 = ctrs + 1536 + (0*8 + g)*32;  // fast-path counters (128B-spaced)
  unsigned int* FCB  = ctrs + 1536 + (1*8 + g)*32;
  unsigned int* FCC  = ctrs + 1536 + (2*8 + g)*32;
  unsigned int* FCA1 = ctrs + 1536 + (3*8 + g)*32;

  // ---- one-time self-test of the EXACT fast-path sequence ----
  if (tid == 0){
    int xcc;
    asm volatile("s_getreg_b32 %0, hwreg(HW_REG_XCC_ID)" : "=s"(xcc));
    unsigned int* testw = ctrs + 1024 + g*32;
    unsigned int* armed = testw + 16;
    if (xcc != g)
      __hip_atomic_fetch_or(badf, 1u, __ATOMIC_RELAXED, __HIP_MEMORY_SCOPE_AGENT);
    __hip_atomic_fetch_add(arrive1, 1u, __ATOMIC_ACQ_REL, __HIP_MEMORY_SCOPE_AGENT);
    int t1 = 0;
    for (int i = 0; i < (1 << 20); ++i){
      if (__hip_atomic_load(arrive1, __ATOMIC_ACQUIRE, __HIP_MEMORY_SCOPE_AGENT) >= 192u){ t1 = 1; break; }
      __builtin_amdgcn_s_sleep(2);
    }
    if (!t1) __hip_atomic_fetch_or(badf, 1u, __ATOMIC_RELAXED, __HIP_MEMORY_SCOPE_AGENT);
    unsigned magic = 0xC0FFEE00u | (unsigned)g;
    if (sub == 0){                      // producer: sc0 data -> vmcnt -> L2-atomic flag
      asm volatile("global_store_dword %0, %1, off sc0\n\t"
                   "s_waitcnt vmcnt(0)" :: "v"(testw), "v"(magic) : "memory");
      atom_inc(armed);
    }
    int ok = 0;
    for (int i = 0; i < (1 << 15); ++i){
      if (atom_poll(armed) >= 1u){ ok = (ld1_sc0(testw) == magic); break; }
      if (i > 16) __builtin_amdgcn_s_sleep(1);
    }
    if (!ok) __hip_atomic_fetch_or(badf, 1u, __ATOMIC_RELAXED, __HIP_MEMORY_SCOPE_AGENT);
    __hip_atomic_fetch_add(arrive2, 1u, __ATOMIC_ACQ_REL, __HIP_MEMORY_SCOPE_AGENT);
    int t2 = 0;
    for (int i = 0; i < (1 << 20); ++i){
      if (__hip_atomic_load(arrive2, __ATOMIC_ACQUIRE, __HIP_MEMORY_SCOPE_AGENT) >= 192u){ t2 = 1; break; }
      __builtin_amdgcn_s_sleep(2);
    }
    unsigned bad = __hip_atomic_load(badf, __ATOMIC_ACQUIRE, __HIP_MEMORY_SCOPE_AGENT);
    s_fast = (t2 && bad == 0u) ? 1 : 0;
  }
  __syncthreads();
  const bool fast = (s_fast != 0);

  // Resident weight slice as MFMA B-fragments: lane holds W[n0+cl][kk*32+kh*8+0..7]
  const float* Wmat = (role == 0) ? Whh0 : (role == 1) ? Wih1 : Whh1;
  short8 wf[32];
  {
    const float* wr = Wmat + (size_t)(n0 + cl)*Hn + kh*8;
#pragma unroll
    for (int kk = 0; kk < 32; ++kk){
      float4 a = *(const float4*)(wr + kk*32);
      float4 b = *(const float4*)(wr + kk*32 + 4);
      short8 v;
      v[0]=(short)f2bf(a.x); v[1]=(short)f2bf(a.y); v[2]=(short)f2bf(a.z); v[3]=(short)f2bf(a.w);
      v[4]=(short)f2bf(b.x); v[5]=(short)f2bf(b.y); v[6]=(short)f2bf(b.z); v[7]=(short)f2bf(b.w);
      wf[kk] = v;
    }
  }

  if (fast)
    rnn_body<true >(role, g, slot, tid, w, lane, cl, kh, lrow, pre0_ro, bufP, h1buf,
                    bias1, FCA0, FCA1, FCB, FCC, FLA, FLB, FLC, wf, hl, outl);
  else
    rnn_body<false>(role, g, slot, tid, w, lane, cl, kh, lrow, pre0_ro, bufP, h1buf,
                    bias1, FCA0, FCA1, FCB, FCC, FLA, FLB, FLC, wf, hl, outl);
}

// ---------------- FC head: out[b][o] = h2[b][T-1][:] . Wfc[o][:] + bfc[o] ----------------
__global__ void fc_k(const unsigned short* __restrict__ bufP,
                     const float* __restrict__ Wfc, const float* __restrict__ bfc,
                     float* __restrict__ out)
{
  int gw = (blockIdx.x * blockDim.x + threadIdx.x) >> 6;
  int lane = threadIdx.x & 63;
  int b = gw >> 7, o = gw & 127;
  // h2(T-1) lives in pre0 slice T-1, group tile (b>>3), chunk-ordered
  const unsigned short* tile = bufP + ((size_t)(Tn-1)*Bn + (b & ~7))*Hn;
  int r = b & 7;
  const float* wr = Wfc + (size_t)o*Hn;
  float s = 0.f;
  for (int k = lane; k < Hn; k += 64)
    s += bf2f(tile[((k>>3)*8 + r)*8 + (k&7)]) * wr[k];
#pragma unroll
  for (int off = 32; off > 0; off >>= 1) s += __shfl_down(s, off, 64);
  if (lane == 0) out[b*OUTn + o] = s + bfc[o];
}

// ---------------- host ----------------
extern "C" void kernel_launch(void* const* d_in, const int* in_sizes, int n_in,
                              void* d_out, int out_size, void* d_ws, size_t ws_size,
                              hipStream_t stream)
{
  const float* x    = (const float*)d_in[0];
  const float* Wih0 = (const float*)d_in[1];
  const float* Whh0 = (const float*)d_in[2];
  const float* bih0 = (const float*)d_in[3];
  const float* bhh0 = (const float*)d_in[4];
  const float* Wih1 = (const float*)d_in[5];
  const float* Whh1 = (const float*)d_in[6];
  const float* bih1 = (const float*)d_in[7];
  const float* bhh1 = (const float*)d_in[8];
  const float* Wfc  = (const float*)d_in[9];
  const float* bfc  = (const float*)d_in[10];
  float* out = (float*)d_out;

  // workspace (bf16 elements)
  unsigned short* bufP  = (unsigned short*)d_ws;                    // pre0 [T][B][H]; h2 aliases slices
  unsigned short* h1buf = bufP  + (size_t)Bn*Tn*Hn;                 // (T+2)*8 chunk-ordered 16KB tiles
  unsigned short* wih0b = h1buf + (size_t)(Tn+2)*8*8192;            // 1MiB
  float* bias0 = (float*)(wih0b + (size_t)Hn*DINn);
  float* bias1 = bias0 + Hn;
  unsigned int* ctrs = (unsigned int*)(bias1 + Hn);                 // 4096 uints

  hipMemsetAsync(ctrs, 0, 4096*sizeof(unsigned int), stream);

  cvt_bf16x8<<<256, 256, 0, stream>>>(Wih0, wih0b, (long long)Hn*DINn/8);
  bias_combine<<<4, 256, 0, stream>>>(bih0, bhh0, bias0, bih1, bhh1, bias1);

  // pre0 = x @ Wih0^T + bias0, written as [T][B][H]
  dim3 g1(Hn/128, (Bn*Tn)/128);
  gemm_pre0<<<g1, 256, 0, stream>>>(x, wih0b, bias0, bufP, Hn, DINn);

  // fused L0-rec -> pre1-GEMV -> L1-rec pipeline (self-tested XCD-local L2 protocol)
  rnn_fused<<<192, 512, 0, stream>>>(bufP, bufP, h1buf, Whh0, Wih1, Whh1, bias1, ctrs);

  // FC head from h2(T-1) (aliased into pre0 slice T-1)
  fc_k<<<2048, 256, 0, stream>>>(bufP, Wfc, bfc, out);
}